// Round 5
// baseline (297.647 us; speedup 1.0000x reference)
//
#include <hip/hip_runtime.h>
#include <hip/hip_bf16.h>

typedef __attribute__((ext_vector_type(4))) float f32x4;
typedef __attribute__((ext_vector_type(8))) short s16x8;
typedef unsigned short ushort_t;

// ---------- helpers ----------
__device__ __forceinline__ ushort_t f2bf(float f) {
    union { float f; unsigned u; } v; v.f = f;
    unsigned r = v.u + 0x7fffu + ((v.u >> 16) & 1u);   // RNE
    return (ushort_t)(r >> 16);
}

__device__ __forceinline__ void gload16(const ushort_t* g, ushort_t* l) {
    __builtin_amdgcn_global_load_lds(
        (const __attribute__((address_space(1))) unsigned int*)g,
        (__attribute__((address_space(3))) unsigned int*)l,
        16, 0, 0);
}

#define BAR()  asm volatile("s_barrier" ::: "memory")
#define LGK0() do { asm volatile("s_waitcnt lgkmcnt(0)" ::: "memory"); __builtin_amdgcn_sched_barrier(0); } while (0)
#define VMC(n) asm volatile("s_waitcnt vmcnt(" #n ")" ::: "memory")

// ---------- fp32 -> bf16 conversion (8 elems/thread) ----------
__global__ void cvt_bf16(const float* __restrict__ in, ushort_t* __restrict__ out, int n8) {
    int i = blockIdx.x * blockDim.x + threadIdx.x;
    if (i >= n8) return;
    const float4* p = (const float4*)in;
    float4 a = p[2 * i], b = p[2 * i + 1];
    s16x8 v;
    v[0] = (short)f2bf(a.x); v[1] = (short)f2bf(a.y);
    v[2] = (short)f2bf(a.z); v[3] = (short)f2bf(a.w);
    v[4] = (short)f2bf(b.x); v[5] = (short)f2bf(b.y);
    v[6] = (short)f2bf(b.z); v[7] = (short)f2bf(b.w);
    *(s16x8*)(out + (size_t)i * 8) = v;
}

// ---------- RoPE tables ----------
__global__ void rope_tab_k(float* __restrict__ cosT, float* __restrict__ sinT) {
    int i = blockIdx.x * blockDim.x + threadIdx.x;   // 8192 total
    int l = i >> 5, fi = i & 31;
    float inv = powf(10000.f, -2.f * (float)fi / 64.f);
    float ang = (float)l * inv;
    cosT[i] = cosf(ang);
    sinT[i] = sinf(ang);
}

// ---------- 256x256 GEMM, BK=32, 4-buffer deep pipeline ----------
// BM=BN=256, BK=32, 8 waves (2Mx4N), LDS 4 x 32KiB buffers, prefetch depth 3.
// Sync protocol: per K-tile, VMC(8) at END of phase 2 followed by s_barrier —
// the barrier makes the per-wave vmcnt guarantee collective (every wave's
// loads for tile u+1 retired before any wave reads it). VMC before reads
// without a barrier is a cross-wave race (round-4 NaN).

__device__ __forceinline__ void stage32(const ushort_t* __restrict__ src,
                                        ushort_t* chunk, int tid, int kk) {
#pragma unroll
    for (int j = 0; j < 2; ++j) {
        int row = (tid >> 2) + j * 128;
        int gslot = (tid & 3) ^ (row & 3);
        gload16(src + (size_t)row * 1024 + kk + gslot * 8,
                chunk + (size_t)tid * 8 + (size_t)j * 4096);
    }
}

__device__ __forceinline__ s16x8 rdA32(const ushort_t* chunk, int wm, int m, int lane) {
    int row = wm * 128 + m * 16 + (lane & 15);
    int slot = (lane >> 4) ^ (row & 3);
    return *(const s16x8*)&chunk[row * 32 + (slot << 3)];
}
__device__ __forceinline__ s16x8 rdB32(const ushort_t* chunk, int wn, int n, int lane) {
    int row = wn * 64 + n * 16 + (lane & 15);
    int slot = (lane >> 4) ^ (row & 3);
    return *(const s16x8*)&chunk[row * 32 + (slot << 3)];
}

// MODE 0: fused QKV (N=3072 -> q/k/v bf16 + bias + rope on q,k)
// MODE 1: out-proj (N=1024 -> fp32 + bias)
template <int MODE>
__global__ __launch_bounds__(512, 2) void gemm256(const ushort_t* __restrict__ A,
                                                  const ushort_t* __restrict__ Wt,
                                                  const float* __restrict__ bz0,
                                                  const float* __restrict__ bz1,
                                                  const float* __restrict__ bz2,
                                                  ushort_t* __restrict__ o0,
                                                  ushort_t* __restrict__ o1,
                                                  ushort_t* __restrict__ o2,
                                                  float* __restrict__ of,
                                                  const float* __restrict__ cosT,
                                                  const float* __restrict__ sinT,
                                                  int ntn) {
    __shared__ ushort_t lds[4][2][8192];   // [buf][0=A,1=B][256*32]

    const int nwg = 64 * ntn;
    const int orig = blockIdx.x;
    const int wg = (orig % 8) * (nwg / 8) + orig / 8;   // bijective XCD swizzle (nwg%8==0)
    const int tn = wg % ntn, tm = wg / ntn;             // tn fastest: A-panel L2 reuse

    const int tid = threadIdx.x, lane = tid & 63, wid = tid >> 6;
    const int wm = wid >> 2, wn = wid & 3;

    f32x4 acc[8][4];
#pragma unroll
    for (int i = 0; i < 8; ++i)
#pragma unroll
        for (int j = 0; j < 4; ++j) acc[i][j] = (f32x4){0.f, 0.f, 0.f, 0.f};

    const ushort_t* Abase = A + (size_t)(tm * 256) * 1024;
    const ushort_t* Bbase = Wt + (size_t)(tn * 256) * 1024;

    // ---- prologue: stage tiles 0..2 into buffers 0..2; guard tile 0 ----
#pragma unroll
    for (int p = 0; p < 3; ++p) {
        stage32(Abase, &lds[p][0][0], tid, p * 32);
        stage32(Bbase, &lds[p][1][0], tid, p * 32);
    }
    VMC(8);    // retire tile0 A+B (12 outstanding -> 8)
    BAR();     // make it collective

    // ---- main loop: 32 K-tiles, 2 phases each, prefetch distance 3 ----
#pragma unroll 1
    for (int u = 0; u < 32; ++u) {
        const ushort_t* cA = &lds[u & 3][0][0];
        const ushort_t* cB = &lds[u & 3][1][0];
        ushort_t* sA = &lds[(u + 3) & 3][0][0];
        ushort_t* sB = &lds[(u + 3) & 3][1][0];
        const int kt = (u + 3 < 32 ? u + 3 : 31) * 32;   // clamp addr, keep count uniform
        s16x8 b_[4], a_[4], a2_[4];

        // ---- phase 1: B + A m0..3 reads; stage (u+3).A; MFMA m0..3 ----
#pragma unroll
        for (int n = 0; n < 4; ++n) b_[n] = rdB32(cB, wn, n, lane);
#pragma unroll
        for (int m = 0; m < 4; ++m) a_[m] = rdA32(cA, wm, m, lane);
        stage32(Abase, sA, tid, kt);
        BAR(); LGK0();
        __builtin_amdgcn_s_setprio(1);
#pragma unroll
        for (int m = 0; m < 4; ++m)
#pragma unroll
            for (int n = 0; n < 4; ++n)
                acc[m][n] = __builtin_amdgcn_mfma_f32_16x16x32_bf16(a_[m], b_[n], acc[m][n], 0, 0, 0);
        __builtin_amdgcn_s_setprio(0);
        BAR();

        // ---- phase 2: A m4..7 reads; stage (u+3).B; VMC(8)+BAR guards tile u+1 ----
#pragma unroll
        for (int m = 0; m < 4; ++m) a2_[m] = rdA32(cA, wm, m + 4, lane);
        stage32(Bbase, sB, tid, kt);
        VMC(8);    // retire tile (u+1) A+B (12 outstanding -> 8)
        BAR(); LGK0();
        __builtin_amdgcn_s_setprio(1);
#pragma unroll
        for (int m = 0; m < 4; ++m)
#pragma unroll
            for (int n = 0; n < 4; ++n)
                acc[m + 4][n] = __builtin_amdgcn_mfma_f32_16x16x32_bf16(a2_[m], b_[n], acc[m + 4][n], 0, 0, 0);
        __builtin_amdgcn_s_setprio(0);
        BAR();
    }
    VMC(0);

    // ---- epilogue ----
    const int rb0 = tm * 256 + wm * 128 + ((lane >> 4) << 2);
    if (MODE == 0) {
        const int zz = (tn * 256) >> 10;                         // uniform per block
        const float* bias = (zz == 0) ? bz0 : (zz == 1) ? bz1 : bz2;
        ushort_t* outp = (zz == 0) ? o0 : (zz == 1) ? o1 : o2;
        const bool rope = (zz < 2);
        const int cb = (tn & 3) * 256 + wn * 64;
#pragma unroll
        for (int m = 0; m < 8; ++m) {
#pragma unroll
            for (int n = 0; n < 4; ++n) {
                int col = cb + n * 16 + (lane & 15);
                float bv_ = bias[col];
                int rb = rb0 + m * 16;
#pragma unroll
                for (int r = 0; r < 4; ++r) {
                    float v = acc[m][n][r] + bv_;
                    float res;
                    if (rope) {
                        int l = (rb + r) & 255;
                        int fi = (col & 63) >> 1;
                        float c = cosT[l * 32 + fi], s = sinT[l * 32 + fi];
                        float partner = __shfl_xor(v, 1);
                        res = (col & 1) ? (v * c + partner * s) : (v * c - partner * s);
                    } else {
                        res = v;
                    }
                    outp[(size_t)(rb + r) * 1024 + col] = f2bf(res);
                }
            }
        }
    } else {
        const int cb = wn * 64;
        const int cfull = tn * 256 + cb;
#pragma unroll
        for (int m = 0; m < 8; ++m) {
#pragma unroll
            for (int n = 0; n < 4; ++n) {
                int col = cfull + n * 16 + (lane & 15);
                float bv_ = bz0[col];
                int rb = rb0 + m * 16;
#pragma unroll
                for (int r = 0; r < 4; ++r)
                    of[(size_t)(rb + r) * 1024 + col] = acc[m][n][r] + bv_;
            }
        }
    }
}

// ---------- fused causal attention per (b,h) ----------
__global__ __launch_bounds__(512) void attn_kernel(const ushort_t* __restrict__ qb,
                                                   const ushort_t* __restrict__ kb,
                                                   const ushort_t* __restrict__ vb,
                                                   ushort_t* __restrict__ ab) {
    __shared__ ushort_t Ks[256 * 72];
    __shared__ ushort_t Vt[64 * 264];
    __shared__ ushort_t Ps[8][16 * 264];
    const int bh = blockIdx.x, b = bh >> 4, h = bh & 15;
    const int tid = threadIdx.x, lane = tid & 63, wid = tid >> 6;
    const size_t base = (size_t)b * 256 * 1024 + (size_t)h * 64;

#pragma unroll
    for (int it = 0; it < 4; ++it) {
        int c = tid + it * 512;
        int row = c >> 3, seg = c & 7;
        *(s16x8*)&Ks[row * 72 + seg * 8] =
            *(const s16x8*)&kb[base + (size_t)row * 1024 + seg * 8];
    }
#pragma unroll
    for (int it = 0; it < 4; ++it) {
        int c = tid + it * 512;
        int k = c >> 3, seg = c & 7;
        s16x8 v8 = *(const s16x8*)&vb[base + (size_t)k * 1024 + seg * 8];
#pragma unroll
        for (int j = 0; j < 8; ++j)
            Vt[(seg * 8 + j) * 264 + k] = (ushort_t)v8[j];
    }
    __syncthreads();

#pragma unroll
    for (int ch = 0; ch < 2; ++ch) {
        const int q0 = wid * 32 + ch * 16;
        const int ntop = q0 >> 4;
        s16x8 aq0 = *(const s16x8*)&qb[base + (size_t)(q0 + (lane & 15)) * 1024 + ((lane >> 4) << 3)];
        s16x8 aq1 = *(const s16x8*)&qb[base + (size_t)(q0 + (lane & 15)) * 1024 + 32 + ((lane >> 4) << 3)];

        f32x4 sacc[16];
#pragma unroll
        for (int n = 0; n < 16; ++n) sacc[n] = (f32x4){0.f, 0.f, 0.f, 0.f};
#pragma unroll
        for (int n = 0; n < 16; ++n) {
            if (n <= ntop) {
                const int kr = (n * 16 + (lane & 15)) * 72 + ((lane >> 4) << 3);
                s16x8 b0 = *(const s16x8*)&Ks[kr];
                s16x8 b1 = *(const s16x8*)&Ks[kr + 32];
                sacc[n] = __builtin_amdgcn_mfma_f32_16x16x32_bf16(aq0, b0, sacc[n], 0, 0, 0);
                sacc[n] = __builtin_amdgcn_mfma_f32_16x16x32_bf16(aq1, b1, sacc[n], 0, 0, 0);
            }
        }

        float rinv[4];
#pragma unroll
        for (int r = 0; r < 4; ++r) {
            const int row = q0 + ((lane >> 4) << 2) + r;
            float m = -1e30f;
#pragma unroll
            for (int n = 0; n < 16; ++n) {
                int col = n * 16 + (lane & 15);
                float v = (col <= row) ? sacc[n][r] * 0.125f : -1e30f;
                sacc[n][r] = v;
                m = fmaxf(m, v);
            }
            m = fmaxf(m, __shfl_xor(m, 1));
            m = fmaxf(m, __shfl_xor(m, 2));
            m = fmaxf(m, __shfl_xor(m, 4));
            m = fmaxf(m, __shfl_xor(m, 8));
            float sum = 0.f;
#pragma unroll
            for (int n = 0; n < 16; ++n) {
                float p = __expf(sacc[n][r] - m);
                sacc[n][r] = p;
                sum += p;
            }
            sum += __shfl_xor(sum, 1);
            sum += __shfl_xor(sum, 2);
            sum += __shfl_xor(sum, 4);
            sum += __shfl_xor(sum, 8);
            rinv[r] = 1.f / sum;
#pragma unroll
            for (int n = 0; n < 16; ++n)
                Ps[wid][(((lane >> 4) << 2) + r) * 264 + n * 16 + (lane & 15)] = f2bf(sacc[n][r]);
        }
        __syncthreads();

        f32x4 oa[4];
#pragma unroll
        for (int dt = 0; dt < 4; ++dt) oa[dt] = (f32x4){0.f, 0.f, 0.f, 0.f};
        const int kstop = q0 >> 5;
#pragma unroll
        for (int ks = 0; ks < 8; ++ks) {
            if (ks <= kstop) {
                s16x8 pf = *(const s16x8*)&Ps[wid][(lane & 15) * 264 + ks * 32 + ((lane >> 4) << 3)];
#pragma unroll
                for (int dt = 0; dt < 4; ++dt) {
                    s16x8 vf = *(const s16x8*)&Vt[(dt * 16 + (lane & 15)) * 264 + ks * 32 + ((lane >> 4) << 3)];
                    oa[dt] = __builtin_amdgcn_mfma_f32_16x16x32_bf16(pf, vf, oa[dt], 0, 0, 0);
                }
            }
        }
#pragma unroll
        for (int dt = 0; dt < 4; ++dt) {
#pragma unroll
            for (int r = 0; r < 4; ++r) {
                int row = q0 + ((lane >> 4) << 2) + r;
                int col = h * 64 + dt * 16 + (lane & 15);
                ab[(size_t)(b * 256 + row) * 1024 + col] = f2bf(oa[dt][r] * rinv[r]);
            }
        }
        __syncthreads();
    }
}

// ---------- launch ----------
extern "C" void kernel_launch(void* const* d_in, const int* in_sizes, int n_in,
                              void* d_out, int out_size, void* d_ws, size_t ws_size,
                              hipStream_t stream) {
    (void)in_sizes; (void)n_in; (void)out_size;
    const float* x  = (const float*)d_in[0];
    const float* Wq = (const float*)d_in[1];
    const float* bq = (const float*)d_in[2];
    const float* Wk = (const float*)d_in[3];
    const float* bk = (const float*)d_in[4];
    const float* Wv = (const float*)d_in[5];
    const float* bv = (const float*)d_in[6];
    const float* Wo = (const float*)d_in[7];
    const float* bo = (const float*)d_in[8];
    float* out = (float*)d_out;

    const size_t M = 16384, E = 1024;
    char* ws = (char*)d_ws;
    ushort_t* xb   = (ushort_t*)ws;          // M*E (aliased as attn out later)
    ushort_t* wqkv = xb + M * E;             // 3*E*E, concat [Wq;Wk;Wv]
    ushort_t* wob  = wqkv + 3 * E * E;
    ushort_t* qb   = wob + E * E;
    ushort_t* kb   = qb + M * E;
    ushort_t* vb   = kb + M * E;
    float* cosT    = (float*)(vb + M * E);
    float* sinT    = cosT + 256 * 32;
    ushort_t* ab   = xb;

    size_t need = (4 * M * E + 4 * E * E) * sizeof(ushort_t) + 2 * 256 * 32 * sizeof(float);
    if (ws_size < need) return;

    cvt_bf16<<<8192, 256, 0, stream>>>(x, xb, (int)(M * E / 8));
    cvt_bf16<<<512, 256, 0, stream>>>(Wq, wqkv, (int)(E * E / 8));
    cvt_bf16<<<512, 256, 0, stream>>>(Wk, wqkv + E * E, (int)(E * E / 8));
    cvt_bf16<<<512, 256, 0, stream>>>(Wv, wqkv + 2 * E * E, (int)(E * E / 8));
    cvt_bf16<<<512, 256, 0, stream>>>(Wo, wob, (int)(E * E / 8));
    rope_tab_k<<<32, 256, 0, stream>>>(cosT, sinT);

    gemm256<0><<<768, 512, 0, stream>>>(xb, wqkv, bq, bk, bv, qb, kb, vb, nullptr,
                                        cosT, sinT, 12);
    attn_kernel<<<1024, 512, 0, stream>>>(qb, kb, vb, ab);
    gemm256<1><<<256, 512, 0, stream>>>(ab, wob, bo, nullptr, nullptr,
                                        nullptr, nullptr, nullptr, out, nullptr, nullptr, 4);
}

// Round 6
// 281.807 us; speedup vs baseline: 1.0562x; 1.0562x over previous
//
#include <hip/hip_runtime.h>
#include <hip/hip_bf16.h>

typedef __attribute__((ext_vector_type(4))) float f32x4;
typedef __attribute__((ext_vector_type(8))) short s16x8;
typedef unsigned short ushort_t;

// ---------- helpers ----------
__device__ __forceinline__ ushort_t f2bf(float f) {
    union { float f; unsigned u; } v; v.f = f;
    unsigned r = v.u + 0x7fffu + ((v.u >> 16) & 1u);   // RNE
    return (ushort_t)(r >> 16);
}

__device__ __forceinline__ void gload16(const ushort_t* g, ushort_t* l) {
    __builtin_amdgcn_global_load_lds(
        (const __attribute__((address_space(1))) unsigned int*)g,
        (__attribute__((address_space(3))) unsigned int*)l,
        16, 0, 0);
}

#define BAR()  asm volatile("s_barrier" ::: "memory")
#define LGK0() do { asm volatile("s_waitcnt lgkmcnt(0)" ::: "memory"); __builtin_amdgcn_sched_barrier(0); } while (0)
#define VMC(n) asm volatile("s_waitcnt vmcnt(" #n ")" ::: "memory")

// ---------- fp32 -> bf16 conversion (8 elems/thread) ----------
__global__ void cvt_bf16(const float* __restrict__ in, ushort_t* __restrict__ out, int n8) {
    int i = blockIdx.x * blockDim.x + threadIdx.x;
    if (i >= n8) return;
    const float4* p = (const float4*)in;
    float4 a = p[2 * i], b = p[2 * i + 1];
    s16x8 v;
    v[0] = (short)f2bf(a.x); v[1] = (short)f2bf(a.y);
    v[2] = (short)f2bf(a.z); v[3] = (short)f2bf(a.w);
    v[4] = (short)f2bf(b.x); v[5] = (short)f2bf(b.y);
    v[6] = (short)f2bf(b.z); v[7] = (short)f2bf(b.w);
    *(s16x8*)(out + (size_t)i * 8) = v;
}

// ---------- RoPE tables ----------
__global__ void rope_tab_k(float* __restrict__ cosT, float* __restrict__ sinT) {
    int i = blockIdx.x * blockDim.x + threadIdx.x;   // 8192 total
    int l = i >> 5, fi = i & 31;
    float inv = powf(10000.f, -2.f * (float)fi / 64.f);
    float ang = (float)l * inv;
    cosT[i] = cosf(ang);
    sinT[i] = sinf(ang);
}

// ---------- 256x256 GEMM, BK=32, 4-buffer rotation, ONE barrier per K-tile ----
// Sync protocol (race-free by construction):
//  - read buf u&3, stage into buf (u+3)&3 : always disjoint.
//  - WAR hazard (stage at iter u overwrites data read at iter u-1): each
//    wave's reads complete before its iter-(u-1) LGK0; stage issues occur
//    after the iter-u BAR, which all waves reach after that. Safe.
//  - RAW hazard (reads of tile u need all waves' stages landed): VMC(8)
//    before the BAR retires tile u's 4 loads per wave (12 outstanding -> 8);
//    barrier makes it collective.
// Swizzle: f(row) = (row>>1)&3; chunk-pos (4*row+f)&7 covers all 8 positions
// over 8 consecutive rows -> 2 lanes/chunk (free). Source pre-swizzled,
// LDS dest linear (global_load_lds constraint), read XORs the same f.

__device__ __forceinline__ void stage32(const ushort_t* __restrict__ src,
                                        ushort_t* chunk, int tid, int kk) {
#pragma unroll
    for (int j = 0; j < 2; ++j) {
        int row = (tid >> 2) + j * 128;
        int gslot = (tid & 3) ^ ((row >> 1) & 3);
        gload16(src + (size_t)row * 1024 + kk + gslot * 8,
                chunk + (size_t)tid * 8 + (size_t)j * 4096);
    }
}

__device__ __forceinline__ s16x8 rdA32(const ushort_t* chunk, int wm, int m, int lane) {
    int row = wm * 128 + m * 16 + (lane & 15);
    int slot = (lane >> 4) ^ ((row >> 1) & 3);
    return *(const s16x8*)&chunk[row * 32 + (slot << 3)];
}
__device__ __forceinline__ s16x8 rdB32(const ushort_t* chunk, int wn, int n, int lane) {
    int row = wn * 64 + n * 16 + (lane & 15);
    int slot = (lane >> 4) ^ ((row >> 1) & 3);
    return *(const s16x8*)&chunk[row * 32 + (slot << 3)];
}

// MODE 0: fused QKV (N=3072 -> q/k/v bf16 + bias + rope on q,k)
// MODE 1: out-proj (N=1024 -> fp32 + bias)
template <int MODE>
__global__ __launch_bounds__(512, 2) void gemm256(const ushort_t* __restrict__ A,
                                                  const ushort_t* __restrict__ Wt,
                                                  const float* __restrict__ bz0,
                                                  const float* __restrict__ bz1,
                                                  const float* __restrict__ bz2,
                                                  ushort_t* __restrict__ o0,
                                                  ushort_t* __restrict__ o1,
                                                  ushort_t* __restrict__ o2,
                                                  float* __restrict__ of,
                                                  const float* __restrict__ cosT,
                                                  const float* __restrict__ sinT,
                                                  int ntn) {
    __shared__ ushort_t lds[4][2][8192];   // [buf][0=A,1=B][256*32]

    const int nwg = 64 * ntn;
    const int orig = blockIdx.x;
    const int wg = (orig % 8) * (nwg / 8) + orig / 8;   // bijective XCD swizzle (nwg%8==0)
    const int tn = wg % ntn, tm = wg / ntn;             // tn fastest: A-panel L2 reuse

    const int tid = threadIdx.x, lane = tid & 63, wid = tid >> 6;
    const int wm = wid >> 2, wn = wid & 3;

    f32x4 acc[8][4];
#pragma unroll
    for (int i = 0; i < 8; ++i)
#pragma unroll
        for (int j = 0; j < 4; ++j) acc[i][j] = (f32x4){0.f, 0.f, 0.f, 0.f};

    const ushort_t* Abase = A + (size_t)(tm * 256) * 1024;
    const ushort_t* Bbase = Wt + (size_t)(tn * 256) * 1024;

    // ---- prologue: stage tiles 0..2 into buffers 0..2 ----
#pragma unroll
    for (int p = 0; p < 3; ++p) {
        stage32(Abase, &lds[p][0][0], tid, p * 32);
        stage32(Bbase, &lds[p][1][0], tid, p * 32);
    }

    // ---- main loop: 32 K-tiles, ONE barrier each, prefetch distance 3 ----
#pragma unroll 1
    for (int u = 0; u < 32; ++u) {
        const ushort_t* cA = &lds[u & 3][0][0];
        const ushort_t* cB = &lds[u & 3][1][0];
        ushort_t* sA = &lds[(u + 3) & 3][0][0];
        ushort_t* sB = &lds[(u + 3) & 3][1][0];
        const int kt = (u + 3 < 32 ? u + 3 : 31) * 32;   // clamp addr, keep count uniform
        s16x8 b_[4], a_[8];

        VMC(8);    // per-wave: this wave's tile-u loads retired (12 -> 8)
        BAR();     // collective: all waves' tile-u landed; all reads of buf (u+3)&3 done
        stage32(Abase, sA, tid, kt);     // prefetch tile u+3 (async, lands by iter u+3)
        stage32(Bbase, sB, tid, kt);
#pragma unroll
        for (int n = 0; n < 4; ++n) b_[n] = rdB32(cB, wn, n, lane);
#pragma unroll
        for (int m = 0; m < 8; ++m) a_[m] = rdA32(cA, wm, m, lane);
        LGK0();
        __builtin_amdgcn_s_setprio(1);
#pragma unroll
        for (int m = 0; m < 8; ++m)
#pragma unroll
            for (int n = 0; n < 4; ++n)
                acc[m][n] = __builtin_amdgcn_mfma_f32_16x16x32_bf16(a_[m], b_[n], acc[m][n], 0, 0, 0);
        __builtin_amdgcn_s_setprio(0);
    }
    VMC(0);

    // ---- epilogue ----
    const int rb0 = tm * 256 + wm * 128 + ((lane >> 4) << 2);
    if (MODE == 0) {
        const int zz = (tn * 256) >> 10;                         // uniform per block
        const float* bias = (zz == 0) ? bz0 : (zz == 1) ? bz1 : bz2;
        ushort_t* outp = (zz == 0) ? o0 : (zz == 1) ? o1 : o2;
        const bool rope = (zz < 2);
        const int cb = (tn & 3) * 256 + wn * 64;
#pragma unroll
        for (int m = 0; m < 8; ++m) {
#pragma unroll
            for (int n = 0; n < 4; ++n) {
                int col = cb + n * 16 + (lane & 15);
                float bv_ = bias[col];
                int rb = rb0 + m * 16;
#pragma unroll
                for (int r = 0; r < 4; ++r) {
                    float v = acc[m][n][r] + bv_;
                    float res;
                    if (rope) {
                        int l = (rb + r) & 255;
                        int fi = (col & 63) >> 1;
                        float c = cosT[l * 32 + fi], s = sinT[l * 32 + fi];
                        float partner = __shfl_xor(v, 1);
                        res = (col & 1) ? (v * c + partner * s) : (v * c - partner * s);
                    } else {
                        res = v;
                    }
                    outp[(size_t)(rb + r) * 1024 + col] = f2bf(res);
                }
            }
        }
    } else {
        const int cb = wn * 64;
        const int cfull = tn * 256 + cb;
#pragma unroll
        for (int m = 0; m < 8; ++m) {
#pragma unroll
            for (int n = 0; n < 4; ++n) {
                int col = cfull + n * 16 + (lane & 15);
                float bv_ = bz0[col];
                int rb = rb0 + m * 16;
#pragma unroll
                for (int r = 0; r < 4; ++r)
                    of[(size_t)(rb + r) * 1024 + col] = acc[m][n][r] + bv_;
            }
        }
    }
}

// ---------- fused causal attention per (b,h) ----------
__global__ __launch_bounds__(512) void attn_kernel(const ushort_t* __restrict__ qb,
                                                   const ushort_t* __restrict__ kb,
                                                   const ushort_t* __restrict__ vb,
                                                   ushort_t* __restrict__ ab) {
    __shared__ ushort_t Ks[256 * 72];
    __shared__ ushort_t Vt[64 * 264];
    __shared__ ushort_t Ps[8][16 * 264];
    const int bh = blockIdx.x, b = bh >> 4, h = bh & 15;
    const int tid = threadIdx.x, lane = tid & 63, wid = tid >> 6;
    const size_t base = (size_t)b * 256 * 1024 + (size_t)h * 64;

#pragma unroll
    for (int it = 0; it < 4; ++it) {
        int c = tid + it * 512;
        int row = c >> 3, seg = c & 7;
        *(s16x8*)&Ks[row * 72 + seg * 8] =
            *(const s16x8*)&kb[base + (size_t)row * 1024 + seg * 8];
    }
#pragma unroll
    for (int it = 0; it < 4; ++it) {
        int c = tid + it * 512;
        int k = c >> 3, seg = c & 7;
        s16x8 v8 = *(const s16x8*)&vb[base + (size_t)k * 1024 + seg * 8];
#pragma unroll
        for (int j = 0; j < 8; ++j)
            Vt[(seg * 8 + j) * 264 + k] = (ushort_t)v8[j];
    }
    __syncthreads();

#pragma unroll
    for (int ch = 0; ch < 2; ++ch) {
        const int q0 = wid * 32 + ch * 16;
        const int ntop = q0 >> 4;
        s16x8 aq0 = *(const s16x8*)&qb[base + (size_t)(q0 + (lane & 15)) * 1024 + ((lane >> 4) << 3)];
        s16x8 aq1 = *(const s16x8*)&qb[base + (size_t)(q0 + (lane & 15)) * 1024 + 32 + ((lane >> 4) << 3)];

        f32x4 sacc[16];
#pragma unroll
        for (int n = 0; n < 16; ++n) sacc[n] = (f32x4){0.f, 0.f, 0.f, 0.f};
#pragma unroll
        for (int n = 0; n < 16; ++n) {
            if (n <= ntop) {
                const int kr = (n * 16 + (lane & 15)) * 72 + ((lane >> 4) << 3);
                s16x8 b0 = *(const s16x8*)&Ks[kr];
                s16x8 b1 = *(const s16x8*)&Ks[kr + 32];
                sacc[n] = __builtin_amdgcn_mfma_f32_16x16x32_bf16(aq0, b0, sacc[n], 0, 0, 0);
                sacc[n] = __builtin_amdgcn_mfma_f32_16x16x32_bf16(aq1, b1, sacc[n], 0, 0, 0);
            }
        }

        float rinv[4];
#pragma unroll
        for (int r = 0; r < 4; ++r) {
            const int row = q0 + ((lane >> 4) << 2) + r;
            float m = -1e30f;
#pragma unroll
            for (int n = 0; n < 16; ++n) {
                int col = n * 16 + (lane & 15);
                float v = (col <= row) ? sacc[n][r] * 0.125f : -1e30f;
                sacc[n][r] = v;
                m = fmaxf(m, v);
            }
            m = fmaxf(m, __shfl_xor(m, 1));
            m = fmaxf(m, __shfl_xor(m, 2));
            m = fmaxf(m, __shfl_xor(m, 4));
            m = fmaxf(m, __shfl_xor(m, 8));
            float sum = 0.f;
#pragma unroll
            for (int n = 0; n < 16; ++n) {
                float p = __expf(sacc[n][r] - m);
                sacc[n][r] = p;
                sum += p;
            }
            sum += __shfl_xor(sum, 1);
            sum += __shfl_xor(sum, 2);
            sum += __shfl_xor(sum, 4);
            sum += __shfl_xor(sum, 8);
            rinv[r] = 1.f / sum;
#pragma unroll
            for (int n = 0; n < 16; ++n)
                Ps[wid][(((lane >> 4) << 2) + r) * 264 + n * 16 + (lane & 15)] = f2bf(sacc[n][r]);
        }
        __syncthreads();

        f32x4 oa[4];
#pragma unroll
        for (int dt = 0; dt < 4; ++dt) oa[dt] = (f32x4){0.f, 0.f, 0.f, 0.f};
        const int kstop = q0 >> 5;
#pragma unroll
        for (int ks = 0; ks < 8; ++ks) {
            if (ks <= kstop) {
                s16x8 pf = *(const s16x8*)&Ps[wid][(lane & 15) * 264 + ks * 32 + ((lane >> 4) << 3)];
#pragma unroll
                for (int dt = 0; dt < 4; ++dt) {
                    s16x8 vf = *(const s16x8*)&Vt[(dt * 16 + (lane & 15)) * 264 + ks * 32 + ((lane >> 4) << 3)];
                    oa[dt] = __builtin_amdgcn_mfma_f32_16x16x32_bf16(pf, vf, oa[dt], 0, 0, 0);
                }
            }
        }
#pragma unroll
        for (int dt = 0; dt < 4; ++dt) {
#pragma unroll
            for (int r = 0; r < 4; ++r) {
                int row = q0 + ((lane >> 4) << 2) + r;
                int col = h * 64 + dt * 16 + (lane & 15);
                ab[(size_t)(b * 256 + row) * 1024 + col] = f2bf(oa[dt][r] * rinv[r]);
            }
        }
        __syncthreads();
    }
}

// ---------- launch ----------
extern "C" void kernel_launch(void* const* d_in, const int* in_sizes, int n_in,
                              void* d_out, int out_size, void* d_ws, size_t ws_size,
                              hipStream_t stream) {
    (void)in_sizes; (void)n_in; (void)out_size;
    const float* x  = (const float*)d_in[0];
    const float* Wq = (const float*)d_in[1];
    const float* bq = (const float*)d_in[2];
    const float* Wk = (const float*)d_in[3];
    const float* bk = (const float*)d_in[4];
    const float* Wv = (const float*)d_in[5];
    const float* bv = (const float*)d_in[6];
    const float* Wo = (const float*)d_in[7];
    const float* bo = (const float*)d_in[8];
    float* out = (float*)d_out;

    const size_t M = 16384, E = 1024;
    char* ws = (char*)d_ws;
    ushort_t* xb   = (ushort_t*)ws;          // M*E (aliased as attn out later)
    ushort_t* wqkv = xb + M * E;             // 3*E*E, concat [Wq;Wk;Wv]
    ushort_t* wob  = wqkv + 3 * E * E;
    ushort_t* qb   = wob + E * E;
    ushort_t* kb   = qb + M * E;
    ushort_t* vb   = kb + M * E;
    float* cosT    = (float*)(vb + M * E);
    float* sinT    = cosT + 256 * 32;
    ushort_t* ab   = xb;

    size_t need = (4 * M * E + 4 * E * E) * sizeof(ushort_t) + 2 * 256 * 32 * sizeof(float);
    if (ws_size < need) return;

    cvt_bf16<<<8192, 256, 0, stream>>>(x, xb, (int)(M * E / 8));
    cvt_bf16<<<512, 256, 0, stream>>>(Wq, wqkv, (int)(E * E / 8));
    cvt_bf16<<<512, 256, 0, stream>>>(Wk, wqkv + E * E, (int)(E * E / 8));
    cvt_bf16<<<512, 256, 0, stream>>>(Wv, wqkv + 2 * E * E, (int)(E * E / 8));
    cvt_bf16<<<512, 256, 0, stream>>>(Wo, wob, (int)(E * E / 8));
    rope_tab_k<<<32, 256, 0, stream>>>(cosT, sinT);

    gemm256<0><<<768, 512, 0, stream>>>(xb, wqkv, bq, bk, bv, qb, kb, vb, nullptr,
                                        cosT, sinT, 12);
    attn_kernel<<<1024, 512, 0, stream>>>(qb, kb, vb, ab);
    gemm256<1><<<256, 512, 0, stream>>>(ab, wob, bo, nullptr, nullptr,
                                        nullptr, nullptr, nullptr, out, nullptr, nullptr, 4);
}

// Round 7
// 268.692 us; speedup vs baseline: 1.1078x; 1.0488x over previous
//
#include <hip/hip_runtime.h>
#include <hip/hip_bf16.h>

typedef __attribute__((ext_vector_type(4))) float f32x4;
typedef __attribute__((ext_vector_type(8))) short s16x8;
typedef unsigned short ushort_t;

// ---------- helpers ----------
__device__ __forceinline__ ushort_t f2bf(float f) {
    union { float f; unsigned u; } v; v.f = f;
    unsigned r = v.u + 0x7fffu + ((v.u >> 16) & 1u);   // RNE
    return (ushort_t)(r >> 16);
}

__device__ __forceinline__ void gload16(const ushort_t* g, ushort_t* l) {
    __builtin_amdgcn_global_load_lds(
        (const __attribute__((address_space(1))) unsigned int*)g,
        (__attribute__((address_space(3))) unsigned int*)l,
        16, 0, 0);
}

#define BAR()  asm volatile("s_barrier" ::: "memory")
#define LGK0() do { asm volatile("s_waitcnt lgkmcnt(0)" ::: "memory"); __builtin_amdgcn_sched_barrier(0); } while (0)
#define VMC(n) asm volatile("s_waitcnt vmcnt(" #n ")" ::: "memory")

// ---------- fp32 -> bf16 conversion (8 elems/thread) ----------
__global__ void cvt_bf16(const float* __restrict__ in, ushort_t* __restrict__ out, int n8) {
    int i = blockIdx.x * blockDim.x + threadIdx.x;
    if (i >= n8) return;
    const float4* p = (const float4*)in;
    float4 a = p[2 * i], b = p[2 * i + 1];
    s16x8 v;
    v[0] = (short)f2bf(a.x); v[1] = (short)f2bf(a.y);
    v[2] = (short)f2bf(a.z); v[3] = (short)f2bf(a.w);
    v[4] = (short)f2bf(b.x); v[5] = (short)f2bf(b.y);
    v[6] = (short)f2bf(b.z); v[7] = (short)f2bf(b.w);
    *(s16x8*)(out + (size_t)i * 8) = v;
}

// 4 weight matrices (E*E each) -> contiguous bf16 [Wq;Wk;Wv;Wo]
__global__ void cvt_w4(const float* __restrict__ w0, const float* __restrict__ w1,
                       const float* __restrict__ w2, const float* __restrict__ w3,
                       ushort_t* __restrict__ out) {
    const float* src = (blockIdx.y == 0) ? w0 : (blockIdx.y == 1) ? w1
                     : (blockIdx.y == 2) ? w2 : w3;
    ushort_t* dst = out + (size_t)blockIdx.y * 1024 * 1024;
    int i = blockIdx.x * blockDim.x + threadIdx.x;   // 131072 per matrix
    const float4* p = (const float4*)src;
    float4 a = p[2 * i], b = p[2 * i + 1];
    s16x8 v;
    v[0] = (short)f2bf(a.x); v[1] = (short)f2bf(a.y);
    v[2] = (short)f2bf(a.z); v[3] = (short)f2bf(a.w);
    v[4] = (short)f2bf(b.x); v[5] = (short)f2bf(b.y);
    v[6] = (short)f2bf(b.z); v[7] = (short)f2bf(b.w);
    *(s16x8*)(dst + (size_t)i * 8) = v;
}

// ---------- RoPE tables ----------
__global__ void rope_tab_k(float* __restrict__ cosT, float* __restrict__ sinT) {
    int i = blockIdx.x * blockDim.x + threadIdx.x;   // 8192 total
    int l = i >> 5, fi = i & 31;
    float inv = powf(10000.f, -2.f * (float)fi / 64.f);
    float ang = (float)l * inv;
    cosT[i] = cosf(ang);
    sinT[i] = sinf(ang);
}

// ---------- 256x256 faithful 8-phase GEMM, BK=64 ----------
// 8 waves 2Mx4N, wave tile 128x64 (8 m-frags x 4 n-frags x kh0/kh1).
// LDS [buf][A/B][half][128*64] = 128 KiB. Per iter (2 K-tiles of 64): 8 phases,
// each {reads (8 or 4 ds_read_b128); stage 1 half (2 gload_lds); [VMC(2) @p4,p8];
// BAR; lgkm0; setprio; 16 MFMA (kh x m-half quadrant); setprio; BAR}.
// Stage ladder: p1:(u+1).B1 p2:(u+1).A0 p3:(u+1).A1 p4:(u+2).B0 p5:(u+2).B1
// p6:(u+2).A0 p7:(u+2).A1 p8:(u+3).B0 — each after its dest's last-read barrier
// (B-halves of a tile free after its p3-endbar, A-halves after p4-endbar).
// VMC(2)@p4 retires oldest 8 of 10 = tile u+1 complete (first read p5);
// VMC(2)@p8 retires tile u+2 (first read next p1). Tail: clamp tile index to 15
// (writes bit-identical data into already-freed or same-valued halves).

__device__ __forceinline__ void stage_half(const ushort_t* __restrict__ src,
                                           ushort_t* chunk, int tid) {
#pragma unroll
    for (int j = 0; j < 2; ++j) {
        int row = (tid >> 3) + j * 64;
        int gslot = (tid & 7) ^ (row & 7);
        gload16(src + (size_t)row * 1024 + gslot * 8,
                chunk + (size_t)tid * 8 + (size_t)j * 4096);
    }
}

__device__ __forceinline__ s16x8 rdA(const ushort_t* chunk, int m, int kh, int lane) {
    int row = m * 16 + (lane & 15);
    int slot = (kh * 4 + (lane >> 4)) ^ (row & 7);
    return *(const s16x8*)&chunk[row * 64 + (slot << 3)];
}
__device__ __forceinline__ s16x8 rdB(const ushort_t* chunk, int wn, int n, int kh, int lane) {
    int row = (wn & 1) * 64 + n * 16 + (lane & 15);
    int slot = (kh * 4 + (lane >> 4)) ^ (row & 7);
    return *(const s16x8*)&chunk[row * 64 + (slot << 3)];
}

// MODE 0: fused QKV (N=3072 -> q/k/v bf16 + bias + rope on q,k)
// MODE 1: out-proj (N=1024 -> fp32 + bias)
template <int MODE>
__global__ __launch_bounds__(512, 2) void gemm256(const ushort_t* __restrict__ A,
                                                  const ushort_t* __restrict__ Wt,
                                                  const float* __restrict__ bz0,
                                                  const float* __restrict__ bz1,
                                                  const float* __restrict__ bz2,
                                                  ushort_t* __restrict__ o0,
                                                  ushort_t* __restrict__ o1,
                                                  ushort_t* __restrict__ o2,
                                                  float* __restrict__ of,
                                                  const float* __restrict__ cosT,
                                                  const float* __restrict__ sinT,
                                                  int ntn) {
    __shared__ ushort_t lds[2][2][2][8192];   // [buf][0=A,1=B][half][128*64]

    const int nwg = 64 * ntn;
    const int orig = blockIdx.x;
    const int wg = (orig % 8) * (nwg / 8) + orig / 8;   // bijective XCD swizzle (nwg%8==0)
    const int tn = wg % ntn, tm = wg / ntn;             // tn fastest: A-panel L2 reuse

    const int tid = threadIdx.x, lane = tid & 63, wid = tid >> 6;
    const int wm = wid >> 2, wn = wid & 3;

    f32x4 acc[8][4];
#pragma unroll
    for (int i = 0; i < 8; ++i)
#pragma unroll
        for (int j = 0; j < 4; ++j) acc[i][j] = (f32x4){0.f, 0.f, 0.f, 0.f};

    const ushort_t* Abase = A + (size_t)(tm * 256) * 1024;
    const ushort_t* Bbase = Wt + (size_t)(tn * 256) * 1024;

    const ushort_t* cA0 = &lds[0][0][wm][0];
    const ushort_t* cB0 = &lds[0][1][wn >> 1][0];
    const ushort_t* cA1 = &lds[1][0][wm][0];
    const ushort_t* cB1 = &lds[1][1][wn >> 1][0];

#define SHX(tv, buf, mat, half)                                                        \
    stage_half(((mat) ? Bbase : Abase) + (size_t)(half) * 131072 + (size_t)(tv) * 64,  \
               &lds[buf][mat][half][0], tid)

#define RDAL(c, kh) do { _Pragma("unroll") for (int m_ = 0; m_ < 4; ++m_) aL[m_] = rdA(c, m_, kh, lane); } while (0)
#define RDAH(c, kh) do { _Pragma("unroll") for (int m_ = 0; m_ < 4; ++m_) aH[m_] = rdA(c, m_ + 4, kh, lane); } while (0)
#define RDB(c, kh)  do { _Pragma("unroll") for (int n_ = 0; n_ < 4; ++n_) bb[n_] = rdB(c, wn, n_, kh, lane); } while (0)

#define PH(MB, AF)                                                                     \
    do {                                                                               \
        BAR(); LGK0();                                                                 \
        __builtin_amdgcn_s_setprio(1);                                                 \
        _Pragma("unroll") for (int m_ = 0; m_ < 4; ++m_)                               \
        _Pragma("unroll") for (int n_ = 0; n_ < 4; ++n_)                               \
            acc[(MB) + m_][n_] = __builtin_amdgcn_mfma_f32_16x16x32_bf16(              \
                AF[m_], bb[n_], acc[(MB) + m_][n_], 0, 0, 0);                          \
        __builtin_amdgcn_s_setprio(0);                                                 \
        BAR();                                                                         \
    } while (0)

    // ---- prologue: tile0 fully (B0,B1,A0,A1) + tile1.B0; retire tile0 ----
    SHX(0, 0, 1, 0); SHX(0, 0, 1, 1); SHX(0, 0, 0, 0); SHX(0, 0, 0, 1);
    SHX(1, 1, 1, 0);
    VMC(2);
    BAR();

    // ---- main loop: 8 iters x 2 K-tiles (even->buf0, odd->buf1) ----
#pragma unroll 1
    for (int t = 0; t < 8; ++t) {
        const int u1 = 2 * t + 1;
        const int u2 = (2 * t + 2 > 15) ? 15 : 2 * t + 2;
        const int u3 = (2 * t + 3 > 15) ? 15 : 2 * t + 3;
        s16x8 aL[4], aH[4], bb[4];

        RDAL(cA0, 0); RDB(cB0, 0); SHX(u1, 1, 1, 1);          PH(0, aL);  // p1
        RDAH(cA0, 0);              SHX(u1, 1, 0, 0);          PH(4, aH);  // p2
        RDAL(cA0, 1); RDB(cB0, 1); SHX(u1, 1, 0, 1);          PH(0, aL);  // p3
        RDAH(cA0, 1);              SHX(u2, 0, 1, 0); VMC(2);  PH(4, aH);  // p4
        RDAL(cA1, 0); RDB(cB1, 0); SHX(u2, 0, 1, 1);          PH(0, aL);  // p5
        RDAH(cA1, 0);              SHX(u2, 0, 0, 0);          PH(4, aH);  // p6
        RDAL(cA1, 1); RDB(cB1, 1); SHX(u2, 0, 0, 1);          PH(0, aL);  // p7
        RDAH(cA1, 1);              SHX(u3, 1, 1, 0); VMC(2);  PH(4, aH);  // p8
    }
    VMC(0);

#undef SHX
#undef RDAL
#undef RDAH
#undef RDB
#undef PH

    // ---- epilogue ----
    const int rb0 = tm * 256 + wm * 128 + ((lane >> 4) << 2);
    if (MODE == 0) {
        const int zz = (tn * 256) >> 10;                         // uniform per block
        const float* bias = (zz == 0) ? bz0 : (zz == 1) ? bz1 : bz2;
        ushort_t* outp = (zz == 0) ? o0 : (zz == 1) ? o1 : o2;
        const bool rope = (zz < 2);
        const int cb = (tn & 3) * 256 + wn * 64;
#pragma unroll
        for (int m = 0; m < 8; ++m) {
#pragma unroll
            for (int n = 0; n < 4; ++n) {
                int col = cb + n * 16 + (lane & 15);
                float bv_ = bias[col];
                int rb = rb0 + m * 16;
#pragma unroll
                for (int r = 0; r < 4; ++r) {
                    float v = acc[m][n][r] + bv_;
                    float res;
                    if (rope) {
                        int l = (rb + r) & 255;
                        int fi = (col & 63) >> 1;
                        float c = cosT[l * 32 + fi], s = sinT[l * 32 + fi];
                        float partner = __shfl_xor(v, 1);
                        res = (col & 1) ? (v * c + partner * s) : (v * c - partner * s);
                    } else {
                        res = v;
                    }
                    outp[(size_t)(rb + r) * 1024 + col] = f2bf(res);
                }
            }
        }
    } else {
        const int cb = wn * 64;
        const int cfull = tn * 256 + cb;
#pragma unroll
        for (int m = 0; m < 8; ++m) {
#pragma unroll
            for (int n = 0; n < 4; ++n) {
                int col = cfull + n * 16 + (lane & 15);
                float bv_ = bz0[col];
                int rb = rb0 + m * 16;
#pragma unroll
                for (int r = 0; r < 4; ++r)
                    of[(size_t)(rb + r) * 1024 + col] = acc[m][n][r] + bv_;
            }
        }
    }
}

// ---------- fused causal attention per (b,h) ----------
__global__ __launch_bounds__(512) void attn_kernel(const ushort_t* __restrict__ qb,
                                                   const ushort_t* __restrict__ kb,
                                                   const ushort_t* __restrict__ vb,
                                                   ushort_t* __restrict__ ab) {
    __shared__ ushort_t Ks[256 * 72];
    __shared__ ushort_t Vt[64 * 264];
    __shared__ ushort_t Ps[8][16 * 264];
    const int bh = blockIdx.x, b = bh >> 4, h = bh & 15;
    const int tid = threadIdx.x, lane = tid & 63, wid = tid >> 6;
    const size_t base = (size_t)b * 256 * 1024 + (size_t)h * 64;

#pragma unroll
    for (int it = 0; it < 4; ++it) {
        int c = tid + it * 512;
        int row = c >> 3, seg = c & 7;
        *(s16x8*)&Ks[row * 72 + seg * 8] =
            *(const s16x8*)&kb[base + (size_t)row * 1024 + seg * 8];
    }
#pragma unroll
    for (int it = 0; it < 4; ++it) {
        int c = tid + it * 512;
        int k = c >> 3, seg = c & 7;
        s16x8 v8 = *(const s16x8*)&vb[base + (size_t)k * 1024 + seg * 8];
#pragma unroll
        for (int j = 0; j < 8; ++j)
            Vt[(seg * 8 + j) * 264 + k] = (ushort_t)v8[j];
    }
    __syncthreads();

#pragma unroll
    for (int ch = 0; ch < 2; ++ch) {
        const int q0 = wid * 32 + ch * 16;
        const int ntop = q0 >> 4;
        s16x8 aq0 = *(const s16x8*)&qb[base + (size_t)(q0 + (lane & 15)) * 1024 + ((lane >> 4) << 3)];
        s16x8 aq1 = *(const s16x8*)&qb[base + (size_t)(q0 + (lane & 15)) * 1024 + 32 + ((lane >> 4) << 3)];

        f32x4 sacc[16];
#pragma unroll
        for (int n = 0; n < 16; ++n) sacc[n] = (f32x4){0.f, 0.f, 0.f, 0.f};
#pragma unroll
        for (int n = 0; n < 16; ++n) {
            if (n <= ntop) {
                const int kr = (n * 16 + (lane & 15)) * 72 + ((lane >> 4) << 3);
                s16x8 b0 = *(const s16x8*)&Ks[kr];
                s16x8 b1 = *(const s16x8*)&Ks[kr + 32];
                sacc[n] = __builtin_amdgcn_mfma_f32_16x16x32_bf16(aq0, b0, sacc[n], 0, 0, 0);
                sacc[n] = __builtin_amdgcn_mfma_f32_16x16x32_bf16(aq1, b1, sacc[n], 0, 0, 0);
            }
        }

        float rinv[4];
#pragma unroll
        for (int r = 0; r < 4; ++r) {
            const int row = q0 + ((lane >> 4) << 2) + r;
            float m = -1e30f;
#pragma unroll
            for (int n = 0; n < 16; ++n) {
                int col = n * 16 + (lane & 15);
                float v = (col <= row) ? sacc[n][r] * 0.125f : -1e30f;
                sacc[n][r] = v;
                m = fmaxf(m, v);
            }
            m = fmaxf(m, __shfl_xor(m, 1));
            m = fmaxf(m, __shfl_xor(m, 2));
            m = fmaxf(m, __shfl_xor(m, 4));
            m = fmaxf(m, __shfl_xor(m, 8));
            float sum = 0.f;
#pragma unroll
            for (int n = 0; n < 16; ++n) {
                float p = __expf(sacc[n][r] - m);
                sacc[n][r] = p;
                sum += p;
            }
            sum += __shfl_xor(sum, 1);
            sum += __shfl_xor(sum, 2);
            sum += __shfl_xor(sum, 4);
            sum += __shfl_xor(sum, 8);
            rinv[r] = 1.f / sum;
#pragma unroll
            for (int n = 0; n < 16; ++n)
                Ps[wid][(((lane >> 4) << 2) + r) * 264 + n * 16 + (lane & 15)] = f2bf(sacc[n][r]);
        }
        __syncthreads();

        f32x4 oa[4];
#pragma unroll
        for (int dt = 0; dt < 4; ++dt) oa[dt] = (f32x4){0.f, 0.f, 0.f, 0.f};
        const int kstop = q0 >> 5;
#pragma unroll
        for (int ks = 0; ks < 8; ++ks) {
            if (ks <= kstop) {
                s16x8 pf = *(const s16x8*)&Ps[wid][(lane & 15) * 264 + ks * 32 + ((lane >> 4) << 3)];
#pragma unroll
                for (int dt = 0; dt < 4; ++dt) {
                    s16x8 vf = *(const s16x8*)&Vt[(dt * 16 + (lane & 15)) * 264 + ks * 32 + ((lane >> 4) << 3)];
                    oa[dt] = __builtin_amdgcn_mfma_f32_16x16x32_bf16(pf, vf, oa[dt], 0, 0, 0);
                }
            }
        }
#pragma unroll
        for (int dt = 0; dt < 4; ++dt) {
#pragma unroll
            for (int r = 0; r < 4; ++r) {
                int row = q0 + ((lane >> 4) << 2) + r;
                int col = h * 64 + dt * 16 + (lane & 15);
                ab[(size_t)(b * 256 + row) * 1024 + col] = f2bf(oa[dt][r] * rinv[r]);
            }
        }
        __syncthreads();
    }
}

// ---------- launch ----------
extern "C" void kernel_launch(void* const* d_in, const int* in_sizes, int n_in,
                              void* d_out, int out_size, void* d_ws, size_t ws_size,
                              hipStream_t stream) {
    (void)in_sizes; (void)n_in; (void)out_size;
    const float* x  = (const float*)d_in[0];
    const float* Wq = (const float*)d_in[1];
    const float* bq = (const float*)d_in[2];
    const float* Wk = (const float*)d_in[3];
    const float* bk = (const float*)d_in[4];
    const float* Wv = (const float*)d_in[5];
    const float* bv = (const float*)d_in[6];
    const float* Wo = (const float*)d_in[7];
    const float* bo = (const float*)d_in[8];
    float* out = (float*)d_out;

    const size_t M = 16384, E = 1024;
    char* ws = (char*)d_ws;
    ushort_t* xb   = (ushort_t*)ws;          // M*E (aliased as attn out later)
    ushort_t* wqkv = xb + M * E;             // 4*E*E, concat [Wq;Wk;Wv;Wo]
    ushort_t* wob  = wqkv + 3 * E * E;
    ushort_t* qb   = wob + E * E;
    ushort_t* kb   = qb + M * E;
    ushort_t* vb   = kb + M * E;
    float* cosT    = (float*)(vb + M * E);
    float* sinT    = cosT + 256 * 32;
    ushort_t* ab   = xb;

    size_t need = (4 * M * E + 4 * E * E) * sizeof(ushort_t) + 2 * 256 * 32 * sizeof(float);
    if (ws_size < need) return;

    cvt_bf16<<<8192, 256, 0, stream>>>(x, xb, (int)(M * E / 8));
    cvt_w4<<<dim3(512, 4), 256, 0, stream>>>(Wq, Wk, Wv, Wo, wqkv);
    rope_tab_k<<<32, 256, 0, stream>>>(cosT, sinT);

    gemm256<0><<<768, 512, 0, stream>>>(xb, wqkv, bq, bk, bv, qb, kb, vb, nullptr,
                                        cosT, sinT, 12);
    attn_kernel<<<1024, 512, 0, stream>>>(qb, kb, vb, ab);
    gemm256<1><<<256, 512, 0, stream>>>(ab, wob, bo, nullptr, nullptr,
                                        nullptr, nullptr, nullptr, out, nullptr, nullptr, 4);
}

// Round 8
// 258.143 us; speedup vs baseline: 1.1530x; 1.0409x over previous
//
#include <hip/hip_runtime.h>
#include <hip/hip_bf16.h>

typedef __attribute__((ext_vector_type(4))) float f32x4;
typedef __attribute__((ext_vector_type(8))) short s16x8;
typedef unsigned short ushort_t;

// ---------- helpers ----------
__device__ __forceinline__ ushort_t f2bf(float f) {
    union { float f; unsigned u; } v; v.f = f;
    unsigned r = v.u + 0x7fffu + ((v.u >> 16) & 1u);   // RNE
    return (ushort_t)(r >> 16);
}

__device__ __forceinline__ void gload16(const ushort_t* g, ushort_t* l) {
    __builtin_amdgcn_global_load_lds(
        (const __attribute__((address_space(1))) unsigned int*)g,
        (__attribute__((address_space(3))) unsigned int*)l,
        16, 0, 0);
}

#define BAR()  asm volatile("s_barrier" ::: "memory")
#define LGK0() do { asm volatile("s_waitcnt lgkmcnt(0)" ::: "memory"); __builtin_amdgcn_sched_barrier(0); } while (0)
#define VMC(n) asm volatile("s_waitcnt vmcnt(" #n ")" ::: "memory")

// ---------- fp32 -> bf16 conversion (8 elems/thread) ----------
__global__ void cvt_bf16(const float* __restrict__ in, ushort_t* __restrict__ out, int n8) {
    int i = blockIdx.x * blockDim.x + threadIdx.x;
    if (i >= n8) return;
    const float4* p = (const float4*)in;
    float4 a = p[2 * i], b = p[2 * i + 1];
    s16x8 v;
    v[0] = (short)f2bf(a.x); v[1] = (short)f2bf(a.y);
    v[2] = (short)f2bf(a.z); v[3] = (short)f2bf(a.w);
    v[4] = (short)f2bf(b.x); v[5] = (short)f2bf(b.y);
    v[6] = (short)f2bf(b.z); v[7] = (short)f2bf(b.w);
    *(s16x8*)(out + (size_t)i * 8) = v;
}

// 4 weight matrices (E*E each) -> contiguous bf16 [Wq;Wk;Wv;Wo]
__global__ void cvt_w4(const float* __restrict__ w0, const float* __restrict__ w1,
                       const float* __restrict__ w2, const float* __restrict__ w3,
                       ushort_t* __restrict__ out) {
    const float* src = (blockIdx.y == 0) ? w0 : (blockIdx.y == 1) ? w1
                     : (blockIdx.y == 2) ? w2 : w3;
    ushort_t* dst = out + (size_t)blockIdx.y * 1024 * 1024;
    int i = blockIdx.x * blockDim.x + threadIdx.x;   // 131072 per matrix
    const float4* p = (const float4*)src;
    float4 a = p[2 * i], b = p[2 * i + 1];
    s16x8 v;
    v[0] = (short)f2bf(a.x); v[1] = (short)f2bf(a.y);
    v[2] = (short)f2bf(a.z); v[3] = (short)f2bf(a.w);
    v[4] = (short)f2bf(b.x); v[5] = (short)f2bf(b.y);
    v[6] = (short)f2bf(b.z); v[7] = (short)f2bf(b.w);
    *(s16x8*)(dst + (size_t)i * 8) = v;
}

// ---------- RoPE tables ----------
__global__ void rope_tab_k(float* __restrict__ cosT, float* __restrict__ sinT) {
    int i = blockIdx.x * blockDim.x + threadIdx.x;   // 8192 total
    int l = i >> 5, fi = i & 31;
    float inv = powf(10000.f, -2.f * (float)fi / 64.f);
    float ang = (float)l * inv;
    cosT[i] = cosf(ang);
    sinT[i] = sinf(ang);
}

// ---------- 256x256 faithful 8-phase GEMM, BK=64 (unchanged from round 7) ----

__device__ __forceinline__ void stage_half(const ushort_t* __restrict__ src,
                                           ushort_t* chunk, int tid) {
#pragma unroll
    for (int j = 0; j < 2; ++j) {
        int row = (tid >> 3) + j * 64;
        int gslot = (tid & 7) ^ (row & 7);
        gload16(src + (size_t)row * 1024 + gslot * 8,
                chunk + (size_t)tid * 8 + (size_t)j * 4096);
    }
}

__device__ __forceinline__ s16x8 rdA(const ushort_t* chunk, int m, int kh, int lane) {
    int row = m * 16 + (lane & 15);
    int slot = (kh * 4 + (lane >> 4)) ^ (row & 7);
    return *(const s16x8*)&chunk[row * 64 + (slot << 3)];
}
__device__ __forceinline__ s16x8 rdB(const ushort_t* chunk, int wn, int n, int kh, int lane) {
    int row = (wn & 1) * 64 + n * 16 + (lane & 15);
    int slot = (kh * 4 + (lane >> 4)) ^ (row & 7);
    return *(const s16x8*)&chunk[row * 64 + (slot << 3)];
}

// MODE 0: fused QKV (N=3072 -> q/k/v bf16 + bias + rope on q,k)
// MODE 1: out-proj (N=1024 -> fp32 + bias)
template <int MODE>
__global__ __launch_bounds__(512, 2) void gemm256(const ushort_t* __restrict__ A,
                                                  const ushort_t* __restrict__ Wt,
                                                  const float* __restrict__ bz0,
                                                  const float* __restrict__ bz1,
                                                  const float* __restrict__ bz2,
                                                  ushort_t* __restrict__ o0,
                                                  ushort_t* __restrict__ o1,
                                                  ushort_t* __restrict__ o2,
                                                  float* __restrict__ of,
                                                  const float* __restrict__ cosT,
                                                  const float* __restrict__ sinT,
                                                  int ntn) {
    __shared__ ushort_t lds[2][2][2][8192];   // [buf][0=A,1=B][half][128*64]

    const int nwg = 64 * ntn;
    const int orig = blockIdx.x;
    const int wg = (orig % 8) * (nwg / 8) + orig / 8;   // bijective XCD swizzle (nwg%8==0)
    const int tn = wg % ntn, tm = wg / ntn;             // tn fastest: A-panel L2 reuse

    const int tid = threadIdx.x, lane = tid & 63, wid = tid >> 6;
    const int wm = wid >> 2, wn = wid & 3;

    f32x4 acc[8][4];
#pragma unroll
    for (int i = 0; i < 8; ++i)
#pragma unroll
        for (int j = 0; j < 4; ++j) acc[i][j] = (f32x4){0.f, 0.f, 0.f, 0.f};

    const ushort_t* Abase = A + (size_t)(tm * 256) * 1024;
    const ushort_t* Bbase = Wt + (size_t)(tn * 256) * 1024;

    const ushort_t* cA0 = &lds[0][0][wm][0];
    const ushort_t* cB0 = &lds[0][1][wn >> 1][0];
    const ushort_t* cA1 = &lds[1][0][wm][0];
    const ushort_t* cB1 = &lds[1][1][wn >> 1][0];

#define SHX(tv, buf, mat, half)                                                        \
    stage_half(((mat) ? Bbase : Abase) + (size_t)(half) * 131072 + (size_t)(tv) * 64,  \
               &lds[buf][mat][half][0], tid)

#define RDAL(c, kh) do { _Pragma("unroll") for (int m_ = 0; m_ < 4; ++m_) aL[m_] = rdA(c, m_, kh, lane); } while (0)
#define RDAH(c, kh) do { _Pragma("unroll") for (int m_ = 0; m_ < 4; ++m_) aH[m_] = rdA(c, m_ + 4, kh, lane); } while (0)
#define RDB(c, kh)  do { _Pragma("unroll") for (int n_ = 0; n_ < 4; ++n_) bb[n_] = rdB(c, wn, n_, kh, lane); } while (0)

#define PH(MB, AF)                                                                     \
    do {                                                                               \
        BAR(); LGK0();                                                                 \
        __builtin_amdgcn_s_setprio(1);                                                 \
        _Pragma("unroll") for (int m_ = 0; m_ < 4; ++m_)                               \
        _Pragma("unroll") for (int n_ = 0; n_ < 4; ++n_)                               \
            acc[(MB) + m_][n_] = __builtin_amdgcn_mfma_f32_16x16x32_bf16(              \
                AF[m_], bb[n_], acc[(MB) + m_][n_], 0, 0, 0);                          \
        __builtin_amdgcn_s_setprio(0);                                                 \
        BAR();                                                                         \
    } while (0)

    // ---- prologue: tile0 fully (B0,B1,A0,A1) + tile1.B0; retire tile0 ----
    SHX(0, 0, 1, 0); SHX(0, 0, 1, 1); SHX(0, 0, 0, 0); SHX(0, 0, 0, 1);
    SHX(1, 1, 1, 0);
    VMC(2);
    BAR();

    // ---- main loop: 8 iters x 2 K-tiles (even->buf0, odd->buf1) ----
#pragma unroll 1
    for (int t = 0; t < 8; ++t) {
        const int u1 = 2 * t + 1;
        const int u2 = (2 * t + 2 > 15) ? 15 : 2 * t + 2;
        const int u3 = (2 * t + 3 > 15) ? 15 : 2 * t + 3;
        s16x8 aL[4], aH[4], bb[4];

        RDAL(cA0, 0); RDB(cB0, 0); SHX(u1, 1, 1, 1);          PH(0, aL);  // p1
        RDAH(cA0, 0);              SHX(u1, 1, 0, 0);          PH(4, aH);  // p2
        RDAL(cA0, 1); RDB(cB0, 1); SHX(u1, 1, 0, 1);          PH(0, aL);  // p3
        RDAH(cA0, 1);              SHX(u2, 0, 1, 0); VMC(2);  PH(4, aH);  // p4
        RDAL(cA1, 0); RDB(cB1, 0); SHX(u2, 0, 1, 1);          PH(0, aL);  // p5
        RDAH(cA1, 0);              SHX(u2, 0, 0, 0);          PH(4, aH);  // p6
        RDAL(cA1, 1); RDB(cB1, 1); SHX(u2, 0, 0, 1);          PH(0, aL);  // p7
        RDAH(cA1, 1);              SHX(u3, 1, 1, 0); VMC(2);  PH(4, aH);  // p8
    }
    VMC(0);

#undef SHX
#undef RDAL
#undef RDAH
#undef RDB
#undef PH

    // ---- epilogue ----
    const int rb0 = tm * 256 + wm * 128 + ((lane >> 4) << 2);
    if (MODE == 0) {
        const int zz = (tn * 256) >> 10;                         // uniform per block
        const float* bias = (zz == 0) ? bz0 : (zz == 1) ? bz1 : bz2;
        ushort_t* outp = (zz == 0) ? o0 : (zz == 1) ? o1 : o2;
        const bool rope = (zz < 2);
        const int cb = (tn & 3) * 256 + wn * 64;
#pragma unroll
        for (int m = 0; m < 8; ++m) {
#pragma unroll
            for (int n = 0; n < 4; ++n) {
                int col = cb + n * 16 + (lane & 15);
                float bv_ = bias[col];
                int rb = rb0 + m * 16;
#pragma unroll
                for (int r = 0; r < 4; ++r) {
                    float v = acc[m][n][r] + bv_;
                    float res;
                    if (rope) {
                        int l = (rb + r) & 255;
                        int fi = (col & 63) >> 1;
                        float c = cosT[l * 32 + fi], s = sinT[l * 32 + fi];
                        float partner = __shfl_xor(v, 1);
                        res = (col & 1) ? (v * c + partner * s) : (v * c - partner * s);
                    } else {
                        res = v;
                    }
                    outp[(size_t)(rb + r) * 1024 + col] = f2bf(res);
                }
            }
        }
    } else {
        const int cb = wn * 64;
        const int cfull = tn * 256 + cb;
#pragma unroll
        for (int m = 0; m < 8; ++m) {
#pragma unroll
            for (int n = 0; n < 4; ++n) {
                int col = cfull + n * 16 + (lane & 15);
                float bv_ = bz0[col];
                int rb = rb0 + m * 16;
#pragma unroll
                for (int r = 0; r < 4; ++r)
                    of[(size_t)(rb + r) * 1024 + col] = acc[m][n][r] + bv_;
            }
        }
    }
}

// ---------- fused causal attention per (b,h) ----------
// LDS 80,896 B -> 2 blocks/CU. Ps is wave-private (cross-lane transpose within
// one wave): no barriers in the ch loop — only the compiler's lgkmcnt orders
// ds_write -> ds_read. P written/consumed in per-ks 32-col chunks (skips
// causally-masked chunks entirely).
__global__ __launch_bounds__(512, 4) void attn_kernel(const ushort_t* __restrict__ qb,
                                                      const ushort_t* __restrict__ kb,
                                                      const ushort_t* __restrict__ vb,
                                                      ushort_t* __restrict__ ab) {
    __shared__ ushort_t Ks[256 * 72];      // 36864 B, row stride 144 B (16-aligned)
    __shared__ ushort_t Vt[64 * 264];      // 33792 B, row stride 528 B (16-aligned)
    __shared__ ushort_t Ps[8][16 * 40];    // 10240 B, row stride 80 B (16-aligned)
    const int bh = blockIdx.x, b = bh >> 4, h = bh & 15;
    const int tid = threadIdx.x, lane = tid & 63, wid = tid >> 6;
    const size_t base = (size_t)b * 256 * 1024 + (size_t)h * 64;

#pragma unroll
    for (int it = 0; it < 4; ++it) {
        int c = tid + it * 512;
        int row = c >> 3, seg = c & 7;
        *(s16x8*)&Ks[row * 72 + seg * 8] =
            *(const s16x8*)&kb[base + (size_t)row * 1024 + seg * 8];
    }
#pragma unroll
    for (int it = 0; it < 4; ++it) {
        int c = tid + it * 512;
        int k = c >> 3, seg = c & 7;
        s16x8 v8 = *(const s16x8*)&vb[base + (size_t)k * 1024 + seg * 8];
#pragma unroll
        for (int j = 0; j < 8; ++j)
            Vt[(seg * 8 + j) * 264 + k] = (ushort_t)v8[j];
    }
    __syncthreads();   // K/V staged; the only barrier in the kernel

#pragma unroll
    for (int ch = 0; ch < 2; ++ch) {
        const int q0 = wid * 32 + ch * 16;
        const int ntop = q0 >> 4;
        s16x8 aq0 = *(const s16x8*)&qb[base + (size_t)(q0 + (lane & 15)) * 1024 + ((lane >> 4) << 3)];
        s16x8 aq1 = *(const s16x8*)&qb[base + (size_t)(q0 + (lane & 15)) * 1024 + 32 + ((lane >> 4) << 3)];

        f32x4 sacc[16];
#pragma unroll
        for (int n = 0; n < 16; ++n) sacc[n] = (f32x4){0.f, 0.f, 0.f, 0.f};
#pragma unroll
        for (int n = 0; n < 16; ++n) {
            if (n <= ntop) {
                const int kr = (n * 16 + (lane & 15)) * 72 + ((lane >> 4) << 3);
                s16x8 b0 = *(const s16x8*)&Ks[kr];
                s16x8 b1 = *(const s16x8*)&Ks[kr + 32];
                sacc[n] = __builtin_amdgcn_mfma_f32_16x16x32_bf16(aq0, b0, sacc[n], 0, 0, 0);
                sacc[n] = __builtin_amdgcn_mfma_f32_16x16x32_bf16(aq1, b1, sacc[n], 0, 0, 0);
            }
        }

        float rinv[4];
#pragma unroll
        for (int r = 0; r < 4; ++r) {
            const int row = q0 + ((lane >> 4) << 2) + r;
            float m = -1e30f;
#pragma unroll
            for (int n = 0; n < 16; ++n) {
                int col = n * 16 + (lane & 15);
                float v = (col <= row) ? sacc[n][r] * 0.125f : -1e30f;
                sacc[n][r] = v;
                m = fmaxf(m, v);
            }
            m = fmaxf(m, __shfl_xor(m, 1));
            m = fmaxf(m, __shfl_xor(m, 2));
            m = fmaxf(m, __shfl_xor(m, 4));
            m = fmaxf(m, __shfl_xor(m, 8));
            float sum = 0.f;
#pragma unroll
            for (int n = 0; n < 16; ++n) {
                float p = __expf(sacc[n][r] - m);
                sacc[n][r] = p;
                sum += p;
            }
            sum += __shfl_xor(sum, 1);
            sum += __shfl_xor(sum, 2);
            sum += __shfl_xor(sum, 4);
            sum += __shfl_xor(sum, 8);
            rinv[r] = 1.f / sum;
        }

        f32x4 oa[4];
#pragma unroll
        for (int dt = 0; dt < 4; ++dt) oa[dt] = (f32x4){0.f, 0.f, 0.f, 0.f};
        const int kstop = q0 >> 5;
#pragma unroll
        for (int ks = 0; ks < 8; ++ks) {
            if (ks <= kstop) {
                // write this wave's P chunk (cols ks*32..+32) into wave-private Ps
#pragma unroll
                for (int nl = 0; nl < 2; ++nl) {
                    const int n = 2 * ks + nl;
#pragma unroll
                    for (int r = 0; r < 4; ++r)
                        Ps[wid][(((lane >> 4) << 2) + r) * 40 + nl * 16 + (lane & 15)] =
                            f2bf(sacc[n][r]);
                }
                // same-wave ds_write -> ds_read: compiler inserts lgkmcnt
                s16x8 pf = *(const s16x8*)&Ps[wid][(lane & 15) * 40 + ((lane >> 4) << 3)];
#pragma unroll
                for (int dt = 0; dt < 4; ++dt) {
                    s16x8 vf = *(const s16x8*)&Vt[(dt * 16 + (lane & 15)) * 264 + ks * 32 + ((lane >> 4) << 3)];
                    oa[dt] = __builtin_amdgcn_mfma_f32_16x16x32_bf16(pf, vf, oa[dt], 0, 0, 0);
                }
            }
        }
#pragma unroll
        for (int dt = 0; dt < 4; ++dt) {
#pragma unroll
            for (int r = 0; r < 4; ++r) {
                int row = q0 + ((lane >> 4) << 2) + r;
                int col = h * 64 + dt * 16 + (lane & 15);
                ab[(size_t)(b * 256 + row) * 1024 + col] = f2bf(oa[dt][r] * rinv[r]);
            }
        }
    }
}

// ---------- launch ----------
extern "C" void kernel_launch(void* const* d_in, const int* in_sizes, int n_in,
                              void* d_out, int out_size, void* d_ws, size_t ws_size,
                              hipStream_t stream) {
    (void)in_sizes; (void)n_in; (void)out_size;
    const float* x  = (const float*)d_in[0];
    const float* Wq = (const float*)d_in[1];
    const float* bq = (const float*)d_in[2];
    const float* Wk = (const float*)d_in[3];
    const float* bk = (const float*)d_in[4];
    const float* Wv = (const float*)d_in[5];
    const float* bv = (const float*)d_in[6];
    const float* Wo = (const float*)d_in[7];
    const float* bo = (const float*)d_in[8];
    float* out = (float*)d_out;

    const size_t M = 16384, E = 1024;
    char* ws = (char*)d_ws;
    ushort_t* xb   = (ushort_t*)ws;          // M*E (aliased as attn out later)
    ushort_t* wqkv = xb + M * E;             // 4*E*E, concat [Wq;Wk;Wv;Wo]
    ushort_t* wob  = wqkv + 3 * E * E;
    ushort_t* qb   = wob + E * E;
    ushort_t* kb   = qb + M * E;
    ushort_t* vb   = kb + M * E;
    float* cosT    = (float*)(vb + M * E);
    float* sinT    = cosT + 256 * 32;
    ushort_t* ab   = xb;

    size_t need = (4 * M * E + 4 * E * E) * sizeof(ushort_t) + 2 * 256 * 32 * sizeof(float);
    if (ws_size < need) return;

    cvt_bf16<<<8192, 256, 0, stream>>>(x, xb, (int)(M * E / 8));
    cvt_w4<<<dim3(512, 4), 256, 0, stream>>>(Wq, Wk, Wv, Wo, wqkv);
    rope_tab_k<<<32, 256, 0, stream>>>(cosT, sinT);

    gemm256<0><<<768, 512, 0, stream>>>(xb, wqkv, bq, bk, bv, qb, kb, vb, nullptr,
                                        cosT, sinT, 12);
    attn_kernel<<<1024, 512, 0, stream>>>(qb, kb, vb, ab);
    gemm256<1><<<256, 512, 0, stream>>>(ab, wob, bo, nullptr, nullptr,
                                        nullptr, nullptr, nullptr, out, nullptr, nullptr, 4);
}

// Round 9
// 239.717 us; speedup vs baseline: 1.2417x; 1.0769x over previous
//
#include <hip/hip_runtime.h>
#include <hip/hip_bf16.h>

typedef __attribute__((ext_vector_type(4))) float f32x4;
typedef __attribute__((ext_vector_type(8))) short s16x8;
typedef unsigned short ushort_t;

// ---------- helpers ----------
__device__ __forceinline__ ushort_t f2bf(float f) {
    union { float f; unsigned u; } v; v.f = f;
    unsigned r = v.u + 0x7fffu + ((v.u >> 16) & 1u);   // RNE
    return (ushort_t)(r >> 16);
}

__device__ __forceinline__ void gload16(const ushort_t* g, ushort_t* l) {
    __builtin_amdgcn_global_load_lds(
        (const __attribute__((address_space(1))) unsigned int*)g,
        (__attribute__((address_space(3))) unsigned int*)l,
        16, 0, 0);
}

#define BAR()  asm volatile("s_barrier" ::: "memory")
#define LGK0() do { asm volatile("s_waitcnt lgkmcnt(0)" ::: "memory"); __builtin_amdgcn_sched_barrier(0); } while (0)
#define VMC(n) asm volatile("s_waitcnt vmcnt(" #n ")" ::: "memory")

// ---------- fp32 -> bf16 conversion (8 elems/thread) ----------
__global__ void cvt_bf16(const float* __restrict__ in, ushort_t* __restrict__ out, int n8) {
    int i = blockIdx.x * blockDim.x + threadIdx.x;
    if (i >= n8) return;
    const float4* p = (const float4*)in;
    float4 a = p[2 * i], b = p[2 * i + 1];
    s16x8 v;
    v[0] = (short)f2bf(a.x); v[1] = (short)f2bf(a.y);
    v[2] = (short)f2bf(a.z); v[3] = (short)f2bf(a.w);
    v[4] = (short)f2bf(b.x); v[5] = (short)f2bf(b.y);
    v[6] = (short)f2bf(b.z); v[7] = (short)f2bf(b.w);
    *(s16x8*)(out + (size_t)i * 8) = v;
}

// 4 weight matrices (E*E each) -> contiguous bf16 [Wq;Wk;Wv;Wo]
__global__ void cvt_w4(const float* __restrict__ w0, const float* __restrict__ w1,
                       const float* __restrict__ w2, const float* __restrict__ w3,
                       ushort_t* __restrict__ out) {
    const float* src = (blockIdx.y == 0) ? w0 : (blockIdx.y == 1) ? w1
                     : (blockIdx.y == 2) ? w2 : w3;
    ushort_t* dst = out + (size_t)blockIdx.y * 1024 * 1024;
    int i = blockIdx.x * blockDim.x + threadIdx.x;   // 131072 per matrix
    const float4* p = (const float4*)src;
    float4 a = p[2 * i], b = p[2 * i + 1];
    s16x8 v;
    v[0] = (short)f2bf(a.x); v[1] = (short)f2bf(a.y);
    v[2] = (short)f2bf(a.z); v[3] = (short)f2bf(a.w);
    v[4] = (short)f2bf(b.x); v[5] = (short)f2bf(b.y);
    v[6] = (short)f2bf(b.z); v[7] = (short)f2bf(b.w);
    *(s16x8*)(dst + (size_t)i * 8) = v;
}

// ---------- RoPE tables ----------
__global__ void rope_tab_k(float* __restrict__ cosT, float* __restrict__ sinT) {
    int i = blockIdx.x * blockDim.x + threadIdx.x;   // 8192 total
    int l = i >> 5, fi = i & 31;
    float inv = powf(10000.f, -2.f * (float)fi / 64.f);
    float ang = (float)l * inv;
    cosT[i] = cosf(ang);
    sinT[i] = sinf(ang);
}

// ---------- 128x256 GEMM, BK=32, dbuf, 2 blocks/CU ----------
// 8 waves (2Mx4N), wave tile 64x64 -> acc[4][4] = 64 regs; ~120 VGPR total
// (launch_bounds(512,4) => 4 waves/SIMD). LDS 2 x 24 KiB = 48 KiB => 2 blocks/CU.
// One barrier per K-tile: VMC(0)+BAR at tile end guards tile u+1 collectively
// (round-5/6 protocol); co-resident block fills the drain stall (m114 TLP).
// Swizzle f(row)=(row>>1)&3: conflict-free (verified 0 conflicts, round 6).

__device__ __forceinline__ void stageA32(const ushort_t* __restrict__ src,
                                         ushort_t* chunk, int tid, int kk) {
    int row = tid >> 2;                       // 128 rows x 4 slots
    int gslot = (tid & 3) ^ ((row >> 1) & 3);
    gload16(src + (size_t)row * 1024 + kk + gslot * 8, chunk + (size_t)tid * 8);
}
__device__ __forceinline__ void stageB32(const ushort_t* __restrict__ src,
                                         ushort_t* chunk, int tid, int kk) {
#pragma unroll
    for (int j = 0; j < 2; ++j) {
        int row = (tid >> 2) + j * 128;       // 256 rows x 4 slots
        int gslot = (tid & 3) ^ ((row >> 1) & 3);
        gload16(src + (size_t)row * 1024 + kk + gslot * 8,
                chunk + (size_t)tid * 8 + (size_t)j * 4096);
    }
}

__device__ __forceinline__ s16x8 rdA32(const ushort_t* chunk, int wm, int m, int lane) {
    int row = wm * 64 + m * 16 + (lane & 15);
    int slot = (lane >> 4) ^ ((row >> 1) & 3);
    return *(const s16x8*)&chunk[row * 32 + (slot << 3)];
}
__device__ __forceinline__ s16x8 rdB32(const ushort_t* chunk, int wn, int n, int lane) {
    int row = wn * 64 + n * 16 + (lane & 15);
    int slot = (lane >> 4) ^ ((row >> 1) & 3);
    return *(const s16x8*)&chunk[row * 32 + (slot << 3)];
}

// MODE 0: fused QKV (N=3072 -> q/k/v bf16 + bias + rope on q,k), ntn=12
// MODE 1: out-proj (N=1024 -> fp32 + bias), ntn=4
template <int MODE>
__global__ __launch_bounds__(512, 4) void gemm128(const ushort_t* __restrict__ A,
                                                  const ushort_t* __restrict__ Wt,
                                                  const float* __restrict__ bz0,
                                                  const float* __restrict__ bz1,
                                                  const float* __restrict__ bz2,
                                                  ushort_t* __restrict__ o0,
                                                  ushort_t* __restrict__ o1,
                                                  ushort_t* __restrict__ o2,
                                                  float* __restrict__ of,
                                                  const float* __restrict__ cosT,
                                                  const float* __restrict__ sinT,
                                                  int ntn) {
    __shared__ ushort_t lds[2][12288];   // per buf: A [0..4096), B [4096..12288)

    const int nwg = 128 * ntn;
    const int orig = blockIdx.x;
    const int wg = (orig % 8) * (nwg / 8) + orig / 8;   // bijective XCD swizzle (nwg%8==0)
    const int tn = wg % ntn, tm = wg / ntn;             // tn fastest: A-panel L2 reuse

    const int tid = threadIdx.x, lane = tid & 63, wid = tid >> 6;
    const int wm = wid >> 2, wn = wid & 3;

    f32x4 acc[4][4];
#pragma unroll
    for (int i = 0; i < 4; ++i)
#pragma unroll
        for (int j = 0; j < 4; ++j) acc[i][j] = (f32x4){0.f, 0.f, 0.f, 0.f};

    const ushort_t* Abase = A + (size_t)(tm * 128) * 1024;
    const ushort_t* Bbase = Wt + (size_t)(tn * 256) * 1024;

    // ---- prologue: stage tile 0 into buf 0; collective guard ----
    stageA32(Abase, &lds[0][0], tid, 0);
    stageB32(Bbase, &lds[0][4096], tid, 0);
    VMC(0);
    BAR();

    // ---- main loop: 32 K-tiles, one barrier each, depth-1 prefetch ----
#pragma unroll 1
    for (int u = 0; u < 32; ++u) {
        const int cur = u & 1;
        const ushort_t* cA = &lds[cur][0];
        const ushort_t* cB = &lds[cur][4096];
        ushort_t* nA = &lds[cur ^ 1][0];
        ushort_t* nB = &lds[cur ^ 1][4096];
        const int kt = (u + 1 < 32 ? u + 1 : 31) * 32;   // clamp: tail writes unread buf
        s16x8 b_[4], a_[2], a2_[2];

#pragma unroll
        for (int n = 0; n < 4; ++n) b_[n] = rdB32(cB, wn, n, lane);
        a_[0] = rdA32(cA, wm, 0, lane); a_[1] = rdA32(cA, wm, 1, lane);
        stageA32(Abase, nA, tid, kt);
        LGK0();
        __builtin_amdgcn_s_setprio(1);
#pragma unroll
        for (int m = 0; m < 2; ++m)
#pragma unroll
            for (int n = 0; n < 4; ++n)
                acc[m][n] = __builtin_amdgcn_mfma_f32_16x16x32_bf16(a_[m], b_[n], acc[m][n], 0, 0, 0);
        __builtin_amdgcn_s_setprio(0);

        a2_[0] = rdA32(cA, wm, 2, lane); a2_[1] = rdA32(cA, wm, 3, lane);
        stageB32(Bbase, nB, tid, kt);
        LGK0();
        __builtin_amdgcn_s_setprio(1);
#pragma unroll
        for (int m = 0; m < 2; ++m)
#pragma unroll
            for (int n = 0; n < 4; ++n)
                acc[m + 2][n] = __builtin_amdgcn_mfma_f32_16x16x32_bf16(a2_[m], b_[n], acc[m + 2][n], 0, 0, 0);
        __builtin_amdgcn_s_setprio(0);

        VMC(0);    // tile u+1 fully landed (per-wave) ...
        BAR();     // ... made collective; also closes WAR window for next stage
    }

    // ---- epilogue ----
    const int rb0 = tm * 128 + wm * 64 + ((lane >> 4) << 2);
    if (MODE == 0) {
        const int zz = tn >> 2;                                  // uniform per block
        const float* bias = (zz == 0) ? bz0 : (zz == 1) ? bz1 : bz2;
        ushort_t* outp = (zz == 0) ? o0 : (zz == 1) ? o1 : o2;
        const bool rope = (zz < 2);
        const int cb = (tn & 3) * 256 + wn * 64;
#pragma unroll
        for (int m = 0; m < 4; ++m) {
#pragma unroll
            for (int n = 0; n < 4; ++n) {
                int col = cb + n * 16 + (lane & 15);
                float bv_ = bias[col];
                int rb = rb0 + m * 16;
#pragma unroll
                for (int r = 0; r < 4; ++r) {
                    float v = acc[m][n][r] + bv_;
                    float res;
                    if (rope) {
                        int l = (rb + r) & 255;
                        int fi = (col & 63) >> 1;
                        float c = cosT[l * 32 + fi], s = sinT[l * 32 + fi];
                        float partner = __shfl_xor(v, 1);
                        res = (col & 1) ? (v * c + partner * s) : (v * c - partner * s);
                    } else {
                        res = v;
                    }
                    outp[(size_t)(rb + r) * 1024 + col] = f2bf(res);
                }
            }
        }
    } else {
        const int cfull = tn * 256 + wn * 64;
#pragma unroll
        for (int m = 0; m < 4; ++m) {
#pragma unroll
            for (int n = 0; n < 4; ++n) {
                int col = cfull + n * 16 + (lane & 15);
                float bv_ = bz0[col];
                int rb = rb0 + m * 16;
#pragma unroll
                for (int r = 0; r < 4; ++r)
                    of[(size_t)(rb + r) * 1024 + col] = acc[m][n][r] + bv_;
            }
        }
    }
}

// ---------- fused causal attention per (b,h) (unchanged from round 8) ----------
__global__ __launch_bounds__(512, 4) void attn_kernel(const ushort_t* __restrict__ qb,
                                                      const ushort_t* __restrict__ kb,
                                                      const ushort_t* __restrict__ vb,
                                                      ushort_t* __restrict__ ab) {
    __shared__ ushort_t Ks[256 * 72];      // 36864 B
    __shared__ ushort_t Vt[64 * 264];      // 33792 B
    __shared__ ushort_t Ps[8][16 * 40];    // 10240 B
    const int bh = blockIdx.x, b = bh >> 4, h = bh & 15;
    const int tid = threadIdx.x, lane = tid & 63, wid = tid >> 6;
    const size_t base = (size_t)b * 256 * 1024 + (size_t)h * 64;

#pragma unroll
    for (int it = 0; it < 4; ++it) {
        int c = tid + it * 512;
        int row = c >> 3, seg = c & 7;
        *(s16x8*)&Ks[row * 72 + seg * 8] =
            *(const s16x8*)&kb[base + (size_t)row * 1024 + seg * 8];
    }
#pragma unroll
    for (int it = 0; it < 4; ++it) {
        int c = tid + it * 512;
        int k = c >> 3, seg = c & 7;
        s16x8 v8 = *(const s16x8*)&vb[base + (size_t)k * 1024 + seg * 8];
#pragma unroll
        for (int j = 0; j < 8; ++j)
            Vt[(seg * 8 + j) * 264 + k] = (ushort_t)v8[j];
    }
    __syncthreads();   // only barrier in the kernel

#pragma unroll
    for (int ch = 0; ch < 2; ++ch) {
        const int q0 = wid * 32 + ch * 16;
        const int ntop = q0 >> 4;
        s16x8 aq0 = *(const s16x8*)&qb[base + (size_t)(q0 + (lane & 15)) * 1024 + ((lane >> 4) << 3)];
        s16x8 aq1 = *(const s16x8*)&qb[base + (size_t)(q0 + (lane & 15)) * 1024 + 32 + ((lane >> 4) << 3)];

        f32x4 sacc[16];
#pragma unroll
        for (int n = 0; n < 16; ++n) sacc[n] = (f32x4){0.f, 0.f, 0.f, 0.f};
#pragma unroll
        for (int n = 0; n < 16; ++n) {
            if (n <= ntop) {
                const int kr = (n * 16 + (lane & 15)) * 72 + ((lane >> 4) << 3);
                s16x8 b0 = *(const s16x8*)&Ks[kr];
                s16x8 b1 = *(const s16x8*)&Ks[kr + 32];
                sacc[n] = __builtin_amdgcn_mfma_f32_16x16x32_bf16(aq0, b0, sacc[n], 0, 0, 0);
                sacc[n] = __builtin_amdgcn_mfma_f32_16x16x32_bf16(aq1, b1, sacc[n], 0, 0, 0);
            }
        }

        float rinv[4];
#pragma unroll
        for (int r = 0; r < 4; ++r) {
            const int row = q0 + ((lane >> 4) << 2) + r;
            float m = -1e30f;
#pragma unroll
            for (int n = 0; n < 16; ++n) {
                int col = n * 16 + (lane & 15);
                float v = (col <= row) ? sacc[n][r] * 0.125f : -1e30f;
                sacc[n][r] = v;
                m = fmaxf(m, v);
            }
            m = fmaxf(m, __shfl_xor(m, 1));
            m = fmaxf(m, __shfl_xor(m, 2));
            m = fmaxf(m, __shfl_xor(m, 4));
            m = fmaxf(m, __shfl_xor(m, 8));
            float sum = 0.f;
#pragma unroll
            for (int n = 0; n < 16; ++n) {
                float p = __expf(sacc[n][r] - m);
                sacc[n][r] = p;
                sum += p;
            }
            sum += __shfl_xor(sum, 1);
            sum += __shfl_xor(sum, 2);
            sum += __shfl_xor(sum, 4);
            sum += __shfl_xor(sum, 8);
            rinv[r] = 1.f / sum;
        }

        f32x4 oa[4];
#pragma unroll
        for (int dt = 0; dt < 4; ++dt) oa[dt] = (f32x4){0.f, 0.f, 0.f, 0.f};
        const int kstop = q0 >> 5;
#pragma unroll
        for (int ks = 0; ks < 8; ++ks) {
            if (ks <= kstop) {
#pragma unroll
                for (int nl = 0; nl < 2; ++nl) {
                    const int n = 2 * ks + nl;
#pragma unroll
                    for (int r = 0; r < 4; ++r)
                        Ps[wid][(((lane >> 4) << 2) + r) * 40 + nl * 16 + (lane & 15)] =
                            f2bf(sacc[n][r]);
                }
                s16x8 pf = *(const s16x8*)&Ps[wid][(lane & 15) * 40 + ((lane >> 4) << 3)];
#pragma unroll
                for (int dt = 0; dt < 4; ++dt) {
                    s16x8 vf = *(const s16x8*)&Vt[(dt * 16 + (lane & 15)) * 264 + ks * 32 + ((lane >> 4) << 3)];
                    oa[dt] = __builtin_amdgcn_mfma_f32_16x16x32_bf16(pf, vf, oa[dt], 0, 0, 0);
                }
            }
        }
#pragma unroll
        for (int dt = 0; dt < 4; ++dt) {
#pragma unroll
            for (int r = 0; r < 4; ++r) {
                int row = q0 + ((lane >> 4) << 2) + r;
                int col = h * 64 + dt * 16 + (lane & 15);
                ab[(size_t)(b * 256 + row) * 1024 + col] = f2bf(oa[dt][r] * rinv[r]);
            }
        }
    }
}

// ---------- launch ----------
extern "C" void kernel_launch(void* const* d_in, const int* in_sizes, int n_in,
                              void* d_out, int out_size, void* d_ws, size_t ws_size,
                              hipStream_t stream) {
    (void)in_sizes; (void)n_in; (void)out_size;
    const float* x  = (const float*)d_in[0];
    const float* Wq = (const float*)d_in[1];
    const float* bq = (const float*)d_in[2];
    const float* Wk = (const float*)d_in[3];
    const float* bk = (const float*)d_in[4];
    const float* Wv = (const float*)d_in[5];
    const float* bv = (const float*)d_in[6];
    const float* Wo = (const float*)d_in[7];
    const float* bo = (const float*)d_in[8];
    float* out = (float*)d_out;

    const size_t M = 16384, E = 1024;
    char* ws = (char*)d_ws;
    ushort_t* xb   = (ushort_t*)ws;          // M*E (aliased as attn out later)
    ushort_t* wqkv = xb + M * E;             // 4*E*E, concat [Wq;Wk;Wv;Wo]
    ushort_t* wob  = wqkv + 3 * E * E;
    ushort_t* qb   = wob + E * E;
    ushort_t* kb   = qb + M * E;
    ushort_t* vb   = kb + M * E;
    float* cosT    = (float*)(vb + M * E);
    float* sinT    = cosT + 256 * 32;
    ushort_t* ab   = xb;

    size_t need = (4 * M * E + 4 * E * E) * sizeof(ushort_t) + 2 * 256 * 32 * sizeof(float);
    if (ws_size < need) return;

    cvt_bf16<<<8192, 256, 0, stream>>>(x, xb, (int)(M * E / 8));
    cvt_w4<<<dim3(512, 4), 256, 0, stream>>>(Wq, Wk, Wv, Wo, wqkv);
    rope_tab_k<<<32, 256, 0, stream>>>(cosT, sinT);

    gemm128<0><<<1536, 512, 0, stream>>>(xb, wqkv, bq, bk, bv, qb, kb, vb, nullptr,
                                         cosT, sinT, 12);
    attn_kernel<<<1024, 512, 0, stream>>>(qb, kb, vb, ab);
    gemm128<1><<<512, 512, 0, stream>>>(ab, wob, bo, nullptr, nullptr,
                                        nullptr, nullptr, nullptr, out, nullptr, nullptr, 4);
}